// Round 8
// baseline (307.566 us; speedup 1.0000x reference)
//
#include <hip/hip_runtime.h>
#include <hip/hip_bf16.h>
#include <cstdint>
#include <cstddef>

#define NE 8
#define N_TOK 8192
#define D_EMB 1024
#define D_FFN 2048

#define BM 128
#define BN 128
#define BK 32

typedef __attribute__((ext_vector_type(8))) short short8;
typedef __attribute__((ext_vector_type(4))) float f32x4;

__device__ __forceinline__ unsigned short f2bf(float f) {
  union { float f; unsigned int u; } c; c.f = f;
  unsigned int u = c.u;
  unsigned int r = u + 0x7FFFu + ((u >> 16) & 1u);
  return (unsigned short)(r >> 16);
}

__device__ __forceinline__ float bf2f(unsigned short u) {
  union { unsigned int u; float f; } c; c.u = ((unsigned int)u) << 16;
  return c.f;
}

// gelu, tanh-form as sigmoid: x*sig(2c(x+0.044715x^3)); |delta| <= 3e-3 on h,
// ~1.4e-3 after W2 diffusion. ~8 VALU ops vs erff's ~25.
__device__ __forceinline__ float gelu_f(float x) {
  float u = x * x * x * 0.044715f + x;
  float t = __expf(-1.5957691216057308f * u);
  return x * __builtin_amdgcn_rcpf(1.f + t);
}

__device__ __forceinline__ void gll16(const void* g, void* l) {
  __builtin_amdgcn_global_load_lds((const __attribute__((address_space(1))) void*)g,
                                   (__attribute__((address_space(3))) void*)l, 16, 0, 0);
}

#define SB() __builtin_amdgcn_sched_barrier(0)
#define VW(N) { asm volatile("s_waitcnt vmcnt(" #N ")" ::: "memory"); SB(); }
#define BAR() { SB(); __builtin_amdgcn_s_barrier(); SB(); }

// ---- router: fp32 logits, top-2 + renorm gates; fused x->bf16 convert ------
__global__ __launch_bounds__(256) void router_k(const float* __restrict__ x,
                                                const float* __restrict__ rw,
                                                int* __restrict__ ti,
                                                float* __restrict__ tg,
                                                ushort* __restrict__ xb) {
  int w = threadIdx.x >> 6, lane = threadIdx.x & 63;
  int n = blockIdx.x * 4 + w;
  const float4* x4 = (const float4*)(x + (size_t)n * D_EMB);
  ushort4* xb4 = (ushort4*)(xb + (size_t)n * D_EMB);
  const float4* r4 = (const float4*)rw;
  float acc[NE];
#pragma unroll
  for (int e = 0; e < NE; ++e) acc[e] = 0.f;
#pragma unroll
  for (int c = 0; c < 4; ++c) {
    float4 xv = x4[c * 64 + lane];
    ushort4 o;
    o.x = f2bf(xv.x); o.y = f2bf(xv.y); o.z = f2bf(xv.z); o.w = f2bf(xv.w);
    xb4[c * 64 + lane] = o;
#pragma unroll
    for (int e = 0; e < NE; ++e) {
      float4 wv = r4[e * 256 + c * 64 + lane];
      acc[e] += xv.x * wv.x + xv.y * wv.y + xv.z * wv.z + xv.w * wv.w;
    }
  }
#pragma unroll
  for (int e = 0; e < NE; ++e) {
    float v = acc[e];
#pragma unroll
    for (int off = 32; off >= 1; off >>= 1) v += __shfl_xor(v, off);
    acc[e] = v;
  }
  if (lane == 0) {
    int e0 = 0; float v0 = acc[0];
#pragma unroll
    for (int e = 1; e < NE; ++e) if (acc[e] > v0) { v0 = acc[e]; e0 = e; }
    int e1 = -1; float v1 = -1e30f;
#pragma unroll
    for (int e = 0; e < NE; ++e) if (e != e0 && acc[e] > v1) { v1 = acc[e]; e1 = e; }
    float p1 = expf(v1 - v0);          // p(top2)/p(top1)
    float g0 = 1.f / (1.f + p1);
    float g1 = p1 * g0;
    ti[2 * n] = e0; ti[2 * n + 1] = e1;
    tg[2 * n] = g0; tg[2 * n + 1] = g1;
  }
}

// ---- counts: LDS-aggregated histogram, 8 global atomics per block ----------
__global__ __launch_bounds__(256) void hist_k(const int* __restrict__ ti,
                                              int* __restrict__ counts) {
  __shared__ int lc[NE];
  if (threadIdx.x < NE) lc[threadIdx.x] = 0;
  __syncthreads();
  int s = blockIdx.x * 512 + threadIdx.x;
  atomicAdd(&lc[ti[s]], 1);
  atomicAdd(&lc[ti[s + 256]], 1);
  __syncthreads();
  if (threadIdx.x < NE) atomicAdd(&counts[threadIdx.x], lc[threadIdx.x]);
}

__global__ void prefix_k(const int* __restrict__ counts, int* __restrict__ bases,
                         int* __restrict__ cursor) {
  if (threadIdx.x == 0) {
    int s = 0;
    for (int e = 0; e < NE; ++e) { bases[e] = s; cursor[e] = s; s += counts[e]; }
  }
}

// ---- scatter: two-phase; tokS[pos] = s (= token*2 + slot-index) ------------
__global__ __launch_bounds__(256) void scatter_k(const int* __restrict__ ti,
                                                 const float* __restrict__ tg,
                                                 int* __restrict__ cursor,
                                                 int* __restrict__ tokS,
                                                 float* __restrict__ gate) {
  __shared__ int lc[NE], lb[NE];
  if (threadIdx.x < NE) lc[threadIdx.x] = 0;
  __syncthreads();
  int s = blockIdx.x * 256 + threadIdx.x;
  int e = ti[s];
  float g = tg[s];
  int loc = atomicAdd(&lc[e], 1);
  __syncthreads();
  if (threadIdx.x < NE) lb[threadIdx.x] = atomicAdd(&cursor[threadIdx.x], lc[threadIdx.x]);
  __syncthreads();
  int pos = lb[e] + loc;
  tokS[pos] = s;
  gate[pos] = g;
}

// transpose src[R][C] fp32 -> dst[C][R] bf16 (used for W1)
__global__ __launch_bounds__(256) void transpose_bf_k(const float* __restrict__ src,
                                                      ushort* __restrict__ dst,
                                                      int R, int C) {
  __shared__ ushort t[32][33];
  int bx = blockIdx.x, by = blockIdx.y;
  int rl = threadIdx.x >> 3, q = threadIdx.x & 7;
  float4 v = *(const float4*)&src[(size_t)(by * 32 + rl) * C + bx * 32 + q * 4];
  t[rl][q * 4 + 0] = f2bf(v.x);
  t[rl][q * 4 + 1] = f2bf(v.y);
  t[rl][q * 4 + 2] = f2bf(v.z);
  t[rl][q * 4 + 3] = f2bf(v.w);
  __syncthreads();
  ushort4 o;
  o.x = t[q * 4 + 0][rl];
  o.y = t[q * 4 + 1][rl];
  o.z = t[q * 4 + 2][rl];
  o.w = t[q * 4 + 3][rl];
  *(ushort4*)&dst[(size_t)(bx * 32 + rl) * R + by * 32 + q * 4] = o;
}

// transpose W2 [NE*D_FFN][D_EMB] fp32 -> PER-EXPERT [NE][D_EMB][D_FFN] bf16.
// Row stride 4KB (was 32KB in the flat [D_EMB][NE*D_FFN] layout); each
// expert's 4MB block is L2-resident on its XCD (1 expert/XCD swizzle).
__global__ __launch_bounds__(256) void transpose_w2e_k(const float* __restrict__ src,
                                                       ushort* __restrict__ dst) {
  __shared__ ushort t[32][33];
  int bx = blockIdx.x, by = blockIdx.y;     // bx: d/32 (0..31), by: f-rows/32 (0..511)
  int rl = threadIdx.x >> 3, q = threadIdx.x & 7;
  float4 v = *(const float4*)&src[(size_t)(by * 32 + rl) * D_EMB + bx * 32 + q * 4];
  t[rl][q * 4 + 0] = f2bf(v.x);
  t[rl][q * 4 + 1] = f2bf(v.y);
  t[rl][q * 4 + 2] = f2bf(v.z);
  t[rl][q * 4 + 3] = f2bf(v.w);
  __syncthreads();
  int e = by >> 6;                           // 2048 f-rows per expert
  int f0 = (by & 63) * 32;
  size_t eoff = (size_t)e * (D_EMB * D_FFN);
  ushort4 o;
  o.x = t[q * 4 + 0][rl];
  o.y = t[q * 4 + 1][rl];
  o.z = t[q * 4 + 2][rl];
  o.w = t[q * 4 + 3][rl];
  *(ushort4*)&dst[eoff + (size_t)(bx * 32 + rl) * D_FFN + f0 + q * 4] = o;
}

// ===== 128x128 / BK=32 grouped GEMM =========================================
// Slot swizzle phys = slot ^ ((row>>1)&3), both-sides via pre-swizzled global
// col; conflict-free (measured 0). Two K-loop variants:
//  KLOOP : double-buffer, prefetch depth 1, counted vmcnt(4)  [R7, proven]
//  KLOOP3: triple-buffer, prefetch depth 2, counted vmcnt(8) — tile computed
//          was staged TWO tiles (~500cyc) earlier: covers L3-latency gathers.

#define STG(BUF)                                                           \
  { _Pragma("unroll") for (int j_ = 0; j_ < 2; ++j_) {                     \
      gll16(aptr[j_], &Al[BUF][ldso[j_]]);                                 \
      gll16(bptr[j_], &Bl[BUF][ldso[j_]]);                                 \
      aptr[j_] += BK; bptr[j_] += BK;                                      \
    } }

#define CMP(BUF)                                                           \
  { short8 a[4], b[4];                                                     \
    _Pragma("unroll") for (int i_ = 0; i_ < 4; ++i_)                       \
      a[i_] = *(const short8*)&Al[BUF][arow + i_ * 16 * BK];               \
    _Pragma("unroll") for (int j_ = 0; j_ < 4; ++j_)                       \
      b[j_] = *(const short8*)&Bl[BUF][brow + j_ * 16 * BK];               \
    _Pragma("unroll") for (int i_ = 0; i_ < 4; ++i_)                       \
      _Pragma("unroll") for (int j_ = 0; j_ < 4; ++j_)                     \
        acc[i_][j_] = __builtin_amdgcn_mfma_f32_16x16x32_bf16(a[i_], b[j_], acc[i_][j_], 0, 0, 0); \
  }

#define KLOOP(NT)                                                          \
  STG(0);                                                                  \
  for (int ks = 0; ks < (NT) - 2; ks += 2) {                               \
    STG(1); VW(4); BAR(); CMP(0); BAR();                                   \
    STG(0); VW(4); BAR(); CMP(1); BAR();                                   \
  }                                                                        \
  STG(1); VW(4); BAR(); CMP(0); BAR();                                     \
  VW(0); BAR(); CMP(1);

// requires NT % 3 == 2 (NT=32: loop 10x computes t0..t29, tail t30,t31)
#define KLOOP3(NT)                                                         \
  STG(0); STG(1);                                                          \
  for (int ks = 0; ks < (NT) - 2; ks += 3) {                               \
    STG(2); VW(8); BAR(); CMP(0); BAR();                                   \
    STG(0); VW(8); BAR(); CMP(1); BAR();                                   \
    STG(1); VW(8); BAR(); CMP(2); BAR();                                   \
  }                                                                        \
  VW(4); BAR(); CMP(0); BAR();                                             \
  VW(0); BAR(); CMP(1);

// ---------------- grouped GEMM1: h = gelu(x @ W1_e), gathered rows ----------
__global__ __launch_bounds__(256) void gemm1_k(const ushort* __restrict__ xb,
                                               const ushort* __restrict__ w1t,
                                               const int* __restrict__ counts,
                                               const int* __restrict__ bases,
                                               const int* __restrict__ tokS,
                                               ushort* __restrict__ h) {
  int bid = (int)blockIdx.x;
  bid = (bid & 7) * (NE * 1024 / 8) + (bid >> 3);   // XCD-contiguous: 1 expert/XCD
  int e = bid >> 10;            // 64 mt * 16 nt per expert
  int rem = bid & 1023;
  int mt = rem >> 4, nt = rem & 15;
  int count = counts[e];
  if (mt * BM >= count) return;
  int base = bases[e];

  __shared__ ushort Al[3][BM * BK];
  __shared__ ushort Bl[3][BN * BK];

  int tid = threadIdx.x;
  int w = tid >> 6, lane = tid & 63;

  // pre-swizzled source column: slot' = (lane&3) ^ ((lane>>3)&3)  [= (row>>1)&3]
  const int ssw = (((lane & 3) ^ ((lane >> 3) & 3))) * 8;

  const ushort* aptr[2]; const ushort* bptr[2];
  int ldso[2];
#pragma unroll
  for (int j = 0; j < 2; ++j) {
    int rl = w * 32 + j * 16 + (lane >> 2);
    int pr = min(base + mt * BM + rl, base + count - 1);
    int t = tokS[pr] >> 1;
    aptr[j] = xb + (size_t)t * D_EMB + ssw;
    int c = e * D_FFN + nt * BN + rl;
    bptr[j] = w1t + (size_t)c * D_EMB + ssw;
    ldso[j] = (w * 32 + j * 16) * BK;
  }

  f32x4 zero = {0.f, 0.f, 0.f, 0.f};
  f32x4 acc[4][4];
#pragma unroll
  for (int i = 0; i < 4; ++i)
#pragma unroll
    for (int j = 0; j < 4; ++j) acc[i][j] = zero;

  int wm = w >> 1, wn = w & 1;
  // swizzled read: physical slot = (lane>>4) ^ ((row>>1)&3), row low bits = lane&15
  const int rsw = ((lane >> 4) ^ (((lane & 15) >> 1) & 3)) * 8;
  const int arow = (wm * 64 + (lane & 15)) * BK + rsw;
  const int brow = (wn * 64 + (lane & 15)) * BK + rsw;

  KLOOP3(D_EMB / BK);   // 32 tiles, depth-2 prefetch

  int r0 = mt * BM + wm * 64, c0 = nt * BN + wn * 64;
#pragma unroll
  for (int i = 0; i < 4; ++i) {
#pragma unroll
    for (int q = 0; q < 4; ++q) {
      int row = r0 + i * 16 + (lane >> 4) * 4 + q;
      if (row < count) {
        size_t hb = (size_t)(base + row) * D_FFN;
#pragma unroll
        for (int j = 0; j < 4; ++j) {
          h[hb + c0 + j * 16 + (lane & 15)] = f2bf(gelu_f(acc[i][j][q]));
        }
      }
    }
  }
}

// -- grouped GEMM2: y2[tok*2+k] = gate * (h @ W2_e), token-major, bf16 -------
__global__ __launch_bounds__(256) void gemm2_k(const ushort* __restrict__ h,
                                               const ushort* __restrict__ w2te,
                                               const int* __restrict__ counts,
                                               const int* __restrict__ bases,
                                               const int* __restrict__ tokS,
                                               const float* __restrict__ gate,
                                               ushort* __restrict__ y2) {
  int bid = (int)blockIdx.x;
  bid = (bid & 7) * (NE * 512 / 8) + (bid >> 3);    // XCD-contiguous: 1 expert/XCD
  int e = bid >> 9;             // 64 mt * 8 nt per expert
  int rem = bid & 511;
  int mt = rem >> 3, nt = rem & 7;
  int count = counts[e];
  if (mt * BM >= count) return;
  int base = bases[e];

  __shared__ ushort Al[2][BM * BK];
  __shared__ ushort Bl[2][BN * BK];

  int tid = threadIdx.x;
  int w = tid >> 6, lane = tid & 63;

  const int ssw = (((lane & 3) ^ ((lane >> 3) & 3))) * 8;

  const ushort* aptr[2]; const ushort* bptr[2];
  int ldso[2];
#pragma unroll
  for (int j = 0; j < 2; ++j) {
    int rl = w * 32 + j * 16 + (lane >> 2);
    int pr = min(base + mt * BM + rl, base + count - 1);
    aptr[j] = h + (size_t)pr * D_FFN + ssw;
    int d = nt * BN + rl;       // output column (embedding dim)
    bptr[j] = w2te + (size_t)e * (D_EMB * D_FFN) + (size_t)d * D_FFN + ssw;
    ldso[j] = (w * 32 + j * 16) * BK;
  }

  f32x4 zero = {0.f, 0.f, 0.f, 0.f};
  f32x4 acc[4][4];
#pragma unroll
  for (int i = 0; i < 4; ++i)
#pragma unroll
    for (int j = 0; j < 4; ++j) acc[i][j] = zero;

  int wm = w >> 1, wn = w & 1;
  const int rsw = ((lane >> 4) ^ (((lane & 15) >> 1) & 3)) * 8;
  const int arow = (wm * 64 + (lane & 15)) * BK + rsw;
  const int brow = (wn * 64 + (lane & 15)) * BK + rsw;

  KLOOP(D_FFN / BK);   // 64 tiles

  int r0 = mt * BM + wm * 64, c0 = nt * BN + wn * 64;
#pragma unroll
  for (int i = 0; i < 4; ++i) {
#pragma unroll
    for (int q = 0; q < 4; ++q) {
      int row = r0 + i * 16 + (lane >> 4) * 4 + q;
      if (row < count) {
        int pr = base + row;
        float g = gate[pr];
        size_t yb = (size_t)tokS[pr] * D_EMB;   // token-major: row = tok*2+k
#pragma unroll
        for (int j = 0; j < 4; ++j) {
          y2[yb + c0 + j * 16 + (lane & 15)] = f2bf(g * acc[i][j][q]);
        }
      }
    }
  }
}

// ---- combine: out[n] = y2[2n] + y2[2n+1] (streaming, gates pre-applied) ----
__global__ __launch_bounds__(256) void combine_k(const ushort* __restrict__ y2,
                                                 float* __restrict__ out) {
  int n = blockIdx.x;
  const ushort4* r0 = (const ushort4*)(y2 + (size_t)(2 * n) * D_EMB);
  const ushort4* r1 = (const ushort4*)(y2 + (size_t)(2 * n + 1) * D_EMB);
  float4* o = (float4*)(out + (size_t)n * D_EMB);
  int i = threadIdx.x;
  ushort4 a = r0[i], b = r1[i];
  float4 v;
  v.x = bf2f(a.x) + bf2f(b.x);
  v.y = bf2f(a.y) + bf2f(b.y);
  v.z = bf2f(a.z) + bf2f(b.z);
  v.w = bf2f(a.w) + bf2f(b.w);
  o[i] = v;
}

extern "C" void kernel_launch(void* const* d_in, const int* in_sizes, int n_in,
                              void* d_out, int out_size, void* d_ws, size_t ws_size,
                              hipStream_t stream) {
  const float* x  = (const float*)d_in[0];
  const float* rw = (const float*)d_in[1];
  const float* w1 = (const float*)d_in[2];
  const float* w2 = (const float*)d_in[3];
  float* out = (float*)d_out;

  char* ws = (char*)d_ws;
  size_t off = 0;
  auto alloc = [&](size_t bytes) {
    void* p = ws + off;
    off = (off + bytes + 255) & ~(size_t)255;
    return p;
  };
  int*    counts = (int*)alloc(32);
  int*    bases  = (int*)alloc(32);
  int*    cursor = (int*)alloc(32);
  int*    ti     = (int*)alloc((size_t)N_TOK * 2 * sizeof(int));
  float*  tg     = (float*)alloc((size_t)N_TOK * 2 * sizeof(float));
  int*    tokS   = (int*)alloc((size_t)N_TOK * 2 * sizeof(int));
  float*  gate   = (float*)alloc((size_t)N_TOK * 2 * sizeof(float));
  ushort* xb     = (ushort*)alloc((size_t)N_TOK * D_EMB * 2);
  ushort* w1t    = (ushort*)alloc((size_t)D_EMB * NE * D_FFN * 2);
  ushort* w2te   = (ushort*)alloc((size_t)D_EMB * NE * D_FFN * 2);
  ushort* hbuf   = (ushort*)alloc((size_t)N_TOK * 2 * D_FFN * 2);
  ushort* ybuf   = (ushort*)alloc((size_t)N_TOK * 2 * D_EMB * 2);
  (void)ws_size; (void)in_sizes; (void)n_in; (void)out_size;

  hipMemsetAsync(counts, 0, 32, stream);

  router_k<<<N_TOK / 4, 256, 0, stream>>>(x, rw, ti, tg, xb);
  transpose_bf_k<<<dim3(512, 32), 256, 0, stream>>>(w1, w1t, D_EMB, NE * D_FFN);
  transpose_w2e_k<<<dim3(32, 512), 256, 0, stream>>>(w2, w2te);
  hist_k<<<N_TOK * 2 / 512, 256, 0, stream>>>(ti, counts);
  prefix_k<<<1, 64, 0, stream>>>(counts, bases, cursor);
  scatter_k<<<N_TOK * 2 / 256, 256, 0, stream>>>(ti, tg, cursor, tokS, gate);
  gemm1_k<<<NE * 64 * 16, 256, 0, stream>>>(xb, w1t, counts, bases, tokS, hbuf);
  gemm2_k<<<NE * 64 * 8, 256, 0, stream>>>(hbuf, w2te, counts, bases, tokS, gate, ybuf);
  combine_k<<<N_TOK, 256, 0, stream>>>(ybuf, out);
}

// Round 9
// 291.419 us; speedup vs baseline: 1.0554x; 1.0554x over previous
//
#include <hip/hip_runtime.h>
#include <hip/hip_bf16.h>
#include <cstdint>
#include <cstddef>

#define NE 8
#define N_TOK 8192
#define D_EMB 1024
#define D_FFN 2048

#define BM 128
#define BN 128
#define BK 32

typedef __attribute__((ext_vector_type(8))) short short8;
typedef __attribute__((ext_vector_type(4))) float f32x4;

__device__ __forceinline__ unsigned short f2bf(float f) {
  union { float f; unsigned int u; } c; c.f = f;
  unsigned int u = c.u;
  unsigned int r = u + 0x7FFFu + ((u >> 16) & 1u);
  return (unsigned short)(r >> 16);
}

__device__ __forceinline__ float bf2f(unsigned short u) {
  union { unsigned int u; float f; } c; c.u = ((unsigned int)u) << 16;
  return c.f;
}

// gelu, tanh-form as sigmoid: x*sig(2c(x+0.044715x^3)); |delta| <= 3e-3 on h,
// ~1.4e-3 after W2 diffusion. ~8 VALU ops vs erff's ~25.
__device__ __forceinline__ float gelu_f(float x) {
  float u = x * x * x * 0.044715f + x;
  float t = __expf(-1.5957691216057308f * u);
  return x * __builtin_amdgcn_rcpf(1.f + t);
}

__device__ __forceinline__ void gll16(const void* g, void* l) {
  __builtin_amdgcn_global_load_lds((const __attribute__((address_space(1))) void*)g,
                                   (__attribute__((address_space(3))) void*)l, 16, 0, 0);
}

#define SB() __builtin_amdgcn_sched_barrier(0)
#define VW(N) { asm volatile("s_waitcnt vmcnt(" #N ")" ::: "memory"); SB(); }
#define BAR() { SB(); __builtin_amdgcn_s_barrier(); SB(); }

// ---- router: fp32 logits, top-2 + renorm gates; fused x->bf16 convert ------
__global__ __launch_bounds__(256) void router_k(const float* __restrict__ x,
                                                const float* __restrict__ rw,
                                                int* __restrict__ ti,
                                                float* __restrict__ tg,
                                                ushort* __restrict__ xb) {
  int w = threadIdx.x >> 6, lane = threadIdx.x & 63;
  int n = blockIdx.x * 4 + w;
  const float4* x4 = (const float4*)(x + (size_t)n * D_EMB);
  ushort4* xb4 = (ushort4*)(xb + (size_t)n * D_EMB);
  const float4* r4 = (const float4*)rw;
  float acc[NE];
#pragma unroll
  for (int e = 0; e < NE; ++e) acc[e] = 0.f;
#pragma unroll
  for (int c = 0; c < 4; ++c) {
    float4 xv = x4[c * 64 + lane];
    ushort4 o;
    o.x = f2bf(xv.x); o.y = f2bf(xv.y); o.z = f2bf(xv.z); o.w = f2bf(xv.w);
    xb4[c * 64 + lane] = o;
#pragma unroll
    for (int e = 0; e < NE; ++e) {
      float4 wv = r4[e * 256 + c * 64 + lane];
      acc[e] += xv.x * wv.x + xv.y * wv.y + xv.z * wv.z + xv.w * wv.w;
    }
  }
#pragma unroll
  for (int e = 0; e < NE; ++e) {
    float v = acc[e];
#pragma unroll
    for (int off = 32; off >= 1; off >>= 1) v += __shfl_xor(v, off);
    acc[e] = v;
  }
  if (lane == 0) {
    int e0 = 0; float v0 = acc[0];
#pragma unroll
    for (int e = 1; e < NE; ++e) if (acc[e] > v0) { v0 = acc[e]; e0 = e; }
    int e1 = -1; float v1 = -1e30f;
#pragma unroll
    for (int e = 0; e < NE; ++e) if (e != e0 && acc[e] > v1) { v1 = acc[e]; e1 = e; }
    float p1 = expf(v1 - v0);          // p(top2)/p(top1)
    float g0 = 1.f / (1.f + p1);
    float g1 = p1 * g0;
    ti[2 * n] = e0; ti[2 * n + 1] = e1;
    tg[2 * n] = g0; tg[2 * n + 1] = g1;
  }
}

// ---- counts: LDS-aggregated histogram, 8 global atomics per block ----------
__global__ __launch_bounds__(256) void hist_k(const int* __restrict__ ti,
                                              int* __restrict__ counts) {
  __shared__ int lc[NE];
  if (threadIdx.x < NE) lc[threadIdx.x] = 0;
  __syncthreads();
  int s = blockIdx.x * 512 + threadIdx.x;
  atomicAdd(&lc[ti[s]], 1);
  atomicAdd(&lc[ti[s + 256]], 1);
  __syncthreads();
  if (threadIdx.x < NE) atomicAdd(&counts[threadIdx.x], lc[threadIdx.x]);
}

__global__ void prefix_k(const int* __restrict__ counts, int* __restrict__ bases,
                         int* __restrict__ cursor) {
  if (threadIdx.x == 0) {
    int s = 0;
    for (int e = 0; e < NE; ++e) { bases[e] = s; cursor[e] = s; s += counts[e]; }
  }
}

// ---- scatter: two-phase; tokS[pos] = s (= token*2 + slot-index) ------------
__global__ __launch_bounds__(256) void scatter_k(const int* __restrict__ ti,
                                                 const float* __restrict__ tg,
                                                 int* __restrict__ cursor,
                                                 int* __restrict__ tokS,
                                                 float* __restrict__ gate) {
  __shared__ int lc[NE], lb[NE];
  if (threadIdx.x < NE) lc[threadIdx.x] = 0;
  __syncthreads();
  int s = blockIdx.x * 256 + threadIdx.x;
  int e = ti[s];
  float g = tg[s];
  int loc = atomicAdd(&lc[e], 1);
  __syncthreads();
  if (threadIdx.x < NE) lb[threadIdx.x] = atomicAdd(&cursor[threadIdx.x], lc[threadIdx.x]);
  __syncthreads();
  int pos = lb[e] + loc;
  tokS[pos] = s;
  gate[pos] = g;
}

// transpose src[R][C] fp32 -> dst[C][R] bf16 (used for W1)
__global__ __launch_bounds__(256) void transpose_bf_k(const float* __restrict__ src,
                                                      ushort* __restrict__ dst,
                                                      int R, int C) {
  __shared__ ushort t[32][33];
  int bx = blockIdx.x, by = blockIdx.y;
  int rl = threadIdx.x >> 3, q = threadIdx.x & 7;
  float4 v = *(const float4*)&src[(size_t)(by * 32 + rl) * C + bx * 32 + q * 4];
  t[rl][q * 4 + 0] = f2bf(v.x);
  t[rl][q * 4 + 1] = f2bf(v.y);
  t[rl][q * 4 + 2] = f2bf(v.z);
  t[rl][q * 4 + 3] = f2bf(v.w);
  __syncthreads();
  ushort4 o;
  o.x = t[q * 4 + 0][rl];
  o.y = t[q * 4 + 1][rl];
  o.z = t[q * 4 + 2][rl];
  o.w = t[q * 4 + 3][rl];
  *(ushort4*)&dst[(size_t)(bx * 32 + rl) * R + by * 32 + q * 4] = o;
}

// transpose W2 [NE*D_FFN][D_EMB] fp32 -> per-expert [NE][D_EMB][D_FFN] bf16
__global__ __launch_bounds__(256) void transpose_w2e_k(const float* __restrict__ src,
                                                       ushort* __restrict__ dst) {
  __shared__ ushort t[32][33];
  int bx = blockIdx.x, by = blockIdx.y;
  int rl = threadIdx.x >> 3, q = threadIdx.x & 7;
  float4 v = *(const float4*)&src[(size_t)(by * 32 + rl) * D_EMB + bx * 32 + q * 4];
  t[rl][q * 4 + 0] = f2bf(v.x);
  t[rl][q * 4 + 1] = f2bf(v.y);
  t[rl][q * 4 + 2] = f2bf(v.z);
  t[rl][q * 4 + 3] = f2bf(v.w);
  __syncthreads();
  int e = by >> 6;
  int f0 = (by & 63) * 32;
  size_t eoff = (size_t)e * (D_EMB * D_FFN);
  ushort4 o;
  o.x = t[q * 4 + 0][rl];
  o.y = t[q * 4 + 1][rl];
  o.z = t[q * 4 + 2][rl];
  o.w = t[q * 4 + 3][rl];
  *(ushort4*)&dst[eoff + (size_t)(bx * 32 + rl) * D_FFN + f0 + q * 4] = o;
}

// ===== gemm1: 128x128 / BK=32, dbuf + counted vmcnt(4) [proven R7 config] ===

#define STG(BUF)                                                           \
  { _Pragma("unroll") for (int j_ = 0; j_ < 2; ++j_) {                     \
      gll16(aptr[j_], &Al[BUF][ldso[j_]]);                                 \
      gll16(bptr[j_], &Bl[BUF][ldso[j_]]);                                 \
      aptr[j_] += BK; bptr[j_] += BK;                                      \
    } }

#define CMP(BUF)                                                           \
  { short8 a[4], b[4];                                                     \
    _Pragma("unroll") for (int i_ = 0; i_ < 4; ++i_)                       \
      a[i_] = *(const short8*)&Al[BUF][arow + i_ * 16 * BK];               \
    _Pragma("unroll") for (int j_ = 0; j_ < 4; ++j_)                       \
      b[j_] = *(const short8*)&Bl[BUF][brow + j_ * 16 * BK];               \
    _Pragma("unroll") for (int i_ = 0; i_ < 4; ++i_)                       \
      _Pragma("unroll") for (int j_ = 0; j_ < 4; ++j_)                     \
        acc[i_][j_] = __builtin_amdgcn_mfma_f32_16x16x32_bf16(a[i_], b[j_], acc[i_][j_], 0, 0, 0); \
  }

#define KLOOP(NT)                                                          \
  STG(0);                                                                  \
  for (int ks = 0; ks < (NT) - 2; ks += 2) {                               \
    STG(1); VW(4); BAR(); CMP(0); BAR();                                   \
    STG(0); VW(4); BAR(); CMP(1); BAR();                                   \
  }                                                                        \
  STG(1); VW(4); BAR(); CMP(0); BAR();                                     \
  VW(0); BAR(); CMP(1);

__global__ __launch_bounds__(256) void gemm1_k(const ushort* __restrict__ xb,
                                               const ushort* __restrict__ w1t,
                                               const int* __restrict__ counts,
                                               const int* __restrict__ bases,
                                               const int* __restrict__ tokS,
                                               ushort* __restrict__ h) {
  int bid = (int)blockIdx.x;
  bid = (bid & 7) * (NE * 1024 / 8) + (bid >> 3);   // XCD-contiguous: 1 expert/XCD
  int e = bid >> 10;
  int rem = bid & 1023;
  int mt = rem >> 4, nt = rem & 15;
  int count = counts[e];
  if (mt * BM >= count) return;
  int base = bases[e];

  __shared__ ushort Al[2][BM * BK];
  __shared__ ushort Bl[2][BN * BK];

  int tid = threadIdx.x;
  int w = tid >> 6, lane = tid & 63;

  const int ssw = (((lane & 3) ^ ((lane >> 3) & 3))) * 8;

  const ushort* aptr[2]; const ushort* bptr[2];
  int ldso[2];
#pragma unroll
  for (int j = 0; j < 2; ++j) {
    int rl = w * 32 + j * 16 + (lane >> 2);
    int pr = min(base + mt * BM + rl, base + count - 1);
    int t = tokS[pr] >> 1;
    aptr[j] = xb + (size_t)t * D_EMB + ssw;
    int c = e * D_FFN + nt * BN + rl;
    bptr[j] = w1t + (size_t)c * D_EMB + ssw;
    ldso[j] = (w * 32 + j * 16) * BK;
  }

  f32x4 zero = {0.f, 0.f, 0.f, 0.f};
  f32x4 acc[4][4];
#pragma unroll
  for (int i = 0; i < 4; ++i)
#pragma unroll
    for (int j = 0; j < 4; ++j) acc[i][j] = zero;

  int wm = w >> 1, wn = w & 1;
  const int rsw = ((lane >> 4) ^ (((lane & 15) >> 1) & 3)) * 8;
  const int arow = (wm * 64 + (lane & 15)) * BK + rsw;
  const int brow = (wn * 64 + (lane & 15)) * BK + rsw;

  KLOOP(D_EMB / BK);   // 32 tiles

  int r0 = mt * BM + wm * 64, c0 = nt * BN + wn * 64;
#pragma unroll
  for (int i = 0; i < 4; ++i) {
#pragma unroll
    for (int q = 0; q < 4; ++q) {
      int row = r0 + i * 16 + (lane >> 4) * 4 + q;
      if (row < count) {
        size_t hb = (size_t)(base + row) * D_FFN;
#pragma unroll
        for (int j = 0; j < 4; ++j) {
          h[hb + c0 + j * 16 + (lane & 15)] = f2bf(gelu_f(acc[i][j][q]));
        }
      }
    }
  }
}

// ===== gemm2: 256x256 / BK=64 / 8 waves / 4-phase counted schedule ==========
// LDS 128KB dynamic: A[2][256][64] + B[2][256][64] bf16. Wave (wm,wn) owns
// rows wm*128..+128, cols wn*64..+64; acc[8][4]. Slot swizzle: phys = slot ^
// (row&7), both-sides (linear gll dest + pre-swizzled global col + swizzled
// ds_read) — the R6-verified BK=64 pattern (0 conflicts).
// Per K-tile t (read buf c): P1 issues next-tile A (4 gll) then VW(4) (retires
// EXACTLY tile t's 8 loads staged during t-1, keeps the 4 new A-loads in
// flight) then barrier-publish, quadrant MFMA. P2 issues next B. P3/P4 pure
// MFMA. One VW per K-tile, counted; drains to 0 only at the final tile.

#define SA2(ABUF)                                                          \
  { _Pragma("unroll") for (int r_ = 0; r_ < 4; ++r_) {                     \
      gll16(aP[r_], &(ABUF)[(r_ * 64 + (tid >> 3)) * 64 + (tid & 7) * 8]); \
      aP[r_] += 64;                                                        \
    } }

#define SB2(BBUF)                                                          \
  { _Pragma("unroll") for (int r_ = 0; r_ < 4; ++r_) {                     \
      gll16(bP[r_], &(BBUF)[(r_ * 64 + (tid >> 3)) * 64 + (tid & 7) * 8]); \
      bP[r_] += 64;                                                        \
    } }

#define RDA2(DST, ABUF, F0)                                                \
  { _Pragma("unroll") for (int f_ = 0; f_ < 4; ++f_) {                     \
      DST[f_][0] = *(const short8*)&(ABUF)[(wm * 128 + ((F0) + f_) * 16 + l15) * 64 + q0];         \
      DST[f_][1] = *(const short8*)&(ABUF)[(wm * 128 + ((F0) + f_) * 16 + l15) * 64 + (q0 ^ 32)];  \
    } }

#define RDB2(DST, BBUF, G0)                                                \
  { _Pragma("unroll") for (int g_ = 0; g_ < 2; ++g_) {                     \
      DST[g_][0] = *(const short8*)&(BBUF)[(wn * 64 + ((G0) + g_) * 16 + l15) * 64 + q0];          \
      DST[g_][1] = *(const short8*)&(BBUF)[(wn * 64 + ((G0) + g_) * 16 + l15) * 64 + (q0 ^ 32)];   \
    } }

#define QMM(FA, FB, F0, G0)                                                \
  { _Pragma("unroll") for (int f_ = 0; f_ < 4; ++f_)                       \
    _Pragma("unroll") for (int g_ = 0; g_ < 2; ++g_)                       \
    _Pragma("unroll") for (int k_ = 0; k_ < 2; ++k_)                       \
      acc[(F0) + f_][(G0) + g_] = __builtin_amdgcn_mfma_f32_16x16x32_bf16( \
          FA[f_][k_], FB[g_][k_], acc[(F0) + f_][(G0) + g_], 0, 0, 0);     \
  }

// one K-tile: CUR A/B bufs, NXT A/B bufs, DOS = stage next tile (0 on last)
#define T256(CA, CB, NA, NB, DOS)                                          \
  { if (DOS) { SA2(NA); VW(4); } else { VW(0); }                           \
    BAR();                                                                 \
    RDA2(fa, CA, 0); RDB2(fb, CB, 0);                                      \
    QMM(fa, fb, 0, 0);                                                     \
    BAR();                                                                 \
    if (DOS) { SB2(NB); }                                                  \
    RDB2(fb2, CB, 2);                                                      \
    QMM(fa, fb2, 0, 2);                                                    \
    BAR();                                                                 \
    RDA2(fa, CA, 4);                                                       \
    QMM(fa, fb2, 4, 2);                                                    \
    BAR();                                                                 \
    RDB2(fb, CB, 0);                                                       \
    QMM(fa, fb, 4, 0);                                                     \
    BAR(); }

__global__ __launch_bounds__(512) void gemm2_k(const ushort* __restrict__ h,
                                               const ushort* __restrict__ w2te,
                                               const int* __restrict__ counts,
                                               const int* __restrict__ bases,
                                               const int* __restrict__ tokS,
                                               const float* __restrict__ gate,
                                               ushort* __restrict__ y2) {
  int bid = (int)blockIdx.x;
  bid = (bid & 7) * 256 + (bid >> 3);   // XCD-contiguous: 1 expert/XCD
  int e = bid >> 8;
  int rem = bid & 255;
  int mt = rem >> 2, nt = rem & 3;      // mt 0..63, nt 0..3 (N = 1024)
  int count = counts[e];
  if (mt * 256 >= count) return;
  int base = bases[e];

  extern __shared__ ushort smem[];
  ushort* A0_ = smem;                    // [256][64]
  ushort* A1_ = smem + 16384;
  ushort* B0_ = smem + 32768;
  ushort* B1_ = smem + 49152;

  int tid = threadIdx.x;
  int wv = tid >> 6, lane = tid & 63;
  int wm = wv >> 2, wn = wv & 3;
  const int l15 = lane & 15;
  const int q0 = ((lane >> 4) ^ (lane & 7)) * 8;
  const int swc = (((tid & 7) ^ ((tid >> 3) & 7))) * 8;

  const ushort* aP[4]; const ushort* bP[4];
#pragma unroll
  for (int r = 0; r < 4; ++r) {
    int R = r * 64 + (tid >> 3);
    int pr = min(base + mt * 256 + R, base + count - 1);
    aP[r] = h + (size_t)pr * D_FFN + swc;
    int d = nt * 256 + R;               // output column (embedding dim)
    bP[r] = w2te + (size_t)e * (D_EMB * D_FFN) + (size_t)d * D_FFN + swc;
  }

  f32x4 zero = {0.f, 0.f, 0.f, 0.f};
  f32x4 acc[8][4];
#pragma unroll
  for (int i = 0; i < 8; ++i)
#pragma unroll
    for (int j = 0; j < 4; ++j) acc[i][j] = zero;

  short8 fa[4][2], fb[2][2], fb2[2][2];

  SA2(A0_); SB2(B0_);                    // prologue: tile 0 (8 loads)

  const int NT = D_FFN / 64;             // 32 K-tiles
  for (int tp = 0; tp < NT / 2 - 1; ++tp) {
    T256(A0_, B0_, A1_, B1_, 1);
    T256(A1_, B1_, A0_, B0_, 1);
  }
  T256(A0_, B0_, A1_, B1_, 1);           // tile NT-2, stages tile NT-1
  T256(A1_, B1_, A0_, B0_, 0);           // tile NT-1, epilogue drain

  int r0 = mt * 256 + wm * 128, c0 = nt * 256 + wn * 64;
#pragma unroll
  for (int f = 0; f < 8; ++f) {
#pragma unroll
    for (int q = 0; q < 4; ++q) {
      int row = r0 + f * 16 + (lane >> 4) * 4 + q;
      if (row < count) {
        int pr = base + row;
        float g = gate[pr];
        size_t yb = (size_t)tokS[pr] * D_EMB;   // token-major: row = tok*2+k
#pragma unroll
        for (int g_ = 0; g_ < 4; ++g_) {
          y2[yb + c0 + g_ * 16 + l15] = f2bf(g * acc[f][g_][q]);
        }
      }
    }
  }
}

// ---- combine: out[n] = y2[2n] + y2[2n+1] (streaming, gates pre-applied) ----
__global__ __launch_bounds__(256) void combine_k(const ushort* __restrict__ y2,
                                                 float* __restrict__ out) {
  int n = blockIdx.x;
  const ushort4* r0 = (const ushort4*)(y2 + (size_t)(2 * n) * D_EMB);
  const ushort4* r1 = (const ushort4*)(y2 + (size_t)(2 * n + 1) * D_EMB);
  float4* o = (float4*)(out + (size_t)n * D_EMB);
  int i = threadIdx.x;
  ushort4 a = r0[i], b = r1[i];
  float4 v;
  v.x = bf2f(a.x) + bf2f(b.x);
  v.y = bf2f(a.y) + bf2f(b.y);
  v.z = bf2f(a.z) + bf2f(b.z);
  v.w = bf2f(a.w) + bf2f(b.w);
  o[i] = v;
}

extern "C" void kernel_launch(void* const* d_in, const int* in_sizes, int n_in,
                              void* d_out, int out_size, void* d_ws, size_t ws_size,
                              hipStream_t stream) {
  const float* x  = (const float*)d_in[0];
  const float* rw = (const float*)d_in[1];
  const float* w1 = (const float*)d_in[2];
  const float* w2 = (const float*)d_in[3];
  float* out = (float*)d_out;

  char* ws = (char*)d_ws;
  size_t off = 0;
  auto alloc = [&](size_t bytes) {
    void* p = ws + off;
    off = (off + bytes + 255) & ~(size_t)255;
    return p;
  };
  int*    counts = (int*)alloc(32);
  int*    bases  = (int*)alloc(32);
  int*    cursor = (int*)alloc(32);
  int*    ti     = (int*)alloc((size_t)N_TOK * 2 * sizeof(int));
  float*  tg     = (float*)alloc((size_t)N_TOK * 2 * sizeof(float));
  int*    tokS   = (int*)alloc((size_t)N_TOK * 2 * sizeof(int));
  float*  gate   = (float*)alloc((size_t)N_TOK * 2 * sizeof(float));
  ushort* xb     = (ushort*)alloc((size_t)N_TOK * D_EMB * 2);
  ushort* w1t    = (ushort*)alloc((size_t)D_EMB * NE * D_FFN * 2);
  ushort* w2te   = (ushort*)alloc((size_t)D_EMB * NE * D_FFN * 2);
  ushort* hbuf   = (ushort*)alloc((size_t)N_TOK * 2 * D_FFN * 2);
  ushort* ybuf   = (ushort*)alloc((size_t)N_TOK * 2 * D_EMB * 2);
  (void)ws_size; (void)in_sizes; (void)n_in; (void)out_size;

  hipFuncSetAttribute((const void*)gemm2_k, hipFuncAttributeMaxDynamicSharedMemorySize, 131072);

  hipMemsetAsync(counts, 0, 32, stream);

  router_k<<<N_TOK / 4, 256, 0, stream>>>(x, rw, ti, tg, xb);
  transpose_bf_k<<<dim3(512, 32), 256, 0, stream>>>(w1, w1t, D_EMB, NE * D_FFN);
  transpose_w2e_k<<<dim3(32, 512), 256, 0, stream>>>(w2, w2te);
  hist_k<<<N_TOK * 2 / 512, 256, 0, stream>>>(ti, counts);
  prefix_k<<<1, 64, 0, stream>>>(counts, bases, cursor);
  scatter_k<<<N_TOK * 2 / 256, 256, 0, stream>>>(ti, tg, cursor, tokS, gate);
  gemm1_k<<<NE * 64 * 16, 256, 0, stream>>>(xb, w1t, counts, bases, tokS, hbuf);
  gemm2_k<<<NE * 64 * 4, 512, 131072, stream>>>(hbuf, w2te, counts, bases, tokS, gate, ybuf);
  combine_k<<<N_TOK, 256, 0, stream>>>(ybuf, out);
}

// Round 10
// 277.165 us; speedup vs baseline: 1.1097x; 1.0514x over previous
//
#include <hip/hip_runtime.h>
#include <hip/hip_bf16.h>
#include <cstdint>
#include <cstddef>

#define NE 8
#define N_TOK 8192
#define D_EMB 1024
#define D_FFN 2048

#define BM 128
#define BN 128
#define BK 32

typedef __attribute__((ext_vector_type(8))) short short8;
typedef __attribute__((ext_vector_type(4))) float f32x4;

__device__ __forceinline__ unsigned short f2bf(float f) {
  union { float f; unsigned int u; } c; c.f = f;
  unsigned int u = c.u;
  unsigned int r = u + 0x7FFFu + ((u >> 16) & 1u);
  return (unsigned short)(r >> 16);
}

__device__ __forceinline__ float bf2f(unsigned short u) {
  union { unsigned int u; float f; } c; c.u = ((unsigned int)u) << 16;
  return c.f;
}

// gelu, tanh-form as sigmoid: x*sig(2c(x+0.044715x^3)); |delta| <= 3e-3 on h,
// ~1.4e-3 after W2 diffusion. ~8 VALU ops vs erff's ~25.
__device__ __forceinline__ float gelu_f(float x) {
  float u = x * x * x * 0.044715f + x;
  float t = __expf(-1.5957691216057308f * u);
  return x * __builtin_amdgcn_rcpf(1.f + t);
}

__device__ __forceinline__ void gll16(const void* g, void* l) {
  __builtin_amdgcn_global_load_lds((const __attribute__((address_space(1))) void*)g,
                                   (__attribute__((address_space(3))) void*)l, 16, 0, 0);
}

#define SB() __builtin_amdgcn_sched_barrier(0)
#define VW(N) { asm volatile("s_waitcnt vmcnt(" #N ")" ::: "memory"); SB(); }
#define BAR() { SB(); __builtin_amdgcn_s_barrier(); SB(); }

// ---- router: fp32 logits, top-2 + renorm gates; fused x->bf16 convert ------
__global__ __launch_bounds__(256) void router_k(const float* __restrict__ x,
                                                const float* __restrict__ rw,
                                                int* __restrict__ ti,
                                                float* __restrict__ tg,
                                                ushort* __restrict__ xb) {
  int w = threadIdx.x >> 6, lane = threadIdx.x & 63;
  int n = blockIdx.x * 4 + w;
  const float4* x4 = (const float4*)(x + (size_t)n * D_EMB);
  ushort4* xb4 = (ushort4*)(xb + (size_t)n * D_EMB);
  const float4* r4 = (const float4*)rw;
  float acc[NE];
#pragma unroll
  for (int e = 0; e < NE; ++e) acc[e] = 0.f;
#pragma unroll
  for (int c = 0; c < 4; ++c) {
    float4 xv = x4[c * 64 + lane];
    ushort4 o;
    o.x = f2bf(xv.x); o.y = f2bf(xv.y); o.z = f2bf(xv.z); o.w = f2bf(xv.w);
    xb4[c * 64 + lane] = o;
#pragma unroll
    for (int e = 0; e < NE; ++e) {
      float4 wv = r4[e * 256 + c * 64 + lane];
      acc[e] += xv.x * wv.x + xv.y * wv.y + xv.z * wv.z + xv.w * wv.w;
    }
  }
#pragma unroll
  for (int e = 0; e < NE; ++e) {
    float v = acc[e];
#pragma unroll
    for (int off = 32; off >= 1; off >>= 1) v += __shfl_xor(v, off);
    acc[e] = v;
  }
  if (lane == 0) {
    int e0 = 0; float v0 = acc[0];
#pragma unroll
    for (int e = 1; e < NE; ++e) if (acc[e] > v0) { v0 = acc[e]; e0 = e; }
    int e1 = -1; float v1 = -1e30f;
#pragma unroll
    for (int e = 0; e < NE; ++e) if (e != e0 && acc[e] > v1) { v1 = acc[e]; e1 = e; }
    float p1 = expf(v1 - v0);          // p(top2)/p(top1)
    float g0 = 1.f / (1.f + p1);
    float g1 = p1 * g0;
    ti[2 * n] = e0; ti[2 * n + 1] = e1;
    tg[2 * n] = g0; tg[2 * n + 1] = g1;
  }
}

// ---- prep: fused {W1-transpose, W2-per-expert-transpose, hist} -------------
// All three are independent once router has written ti. Grid partition:
//   [0, 16384)        : W1 [D_EMB][NE*D_FFN] fp32 -> w1t [NE*D_FFN][D_EMB] bf16
//   [16384, 32768)    : W2 [NE*D_FFN][D_EMB] fp32 -> w2te [NE][D_EMB][D_FFN] bf16
//   [32768, 32800)    : hist (LDS-aggregated, 8 global atomics per block)
__global__ __launch_bounds__(256) void prep_k(const float* __restrict__ w1,
                                              const float* __restrict__ w2,
                                              const int* __restrict__ ti,
                                              ushort* __restrict__ w1t,
                                              ushort* __restrict__ w2te,
                                              int* __restrict__ counts) {
  int b = blockIdx.x;
  if (b >= 32768) {                       // ---- hist ----
    __shared__ int lc[NE];
    if (threadIdx.x < NE) lc[threadIdx.x] = 0;
    __syncthreads();
    int s = (b - 32768) * 512 + threadIdx.x;
    atomicAdd(&lc[ti[s]], 1);
    atomicAdd(&lc[ti[s + 256]], 1);
    __syncthreads();
    if (threadIdx.x < NE) atomicAdd(&counts[threadIdx.x], lc[threadIdx.x]);
    return;
  }
  __shared__ ushort t[32][33];
  int rl = threadIdx.x >> 3, q = threadIdx.x & 7;
  if (b < 16384) {                        // ---- W1 transpose ----
    int bx = b & 511, by = b >> 9;        // src [32*32 rows][512*32 cols]
    const int C = NE * D_FFN;
    float4 v = *(const float4*)&w1[(size_t)(by * 32 + rl) * C + bx * 32 + q * 4];
    t[rl][q * 4 + 0] = f2bf(v.x);
    t[rl][q * 4 + 1] = f2bf(v.y);
    t[rl][q * 4 + 2] = f2bf(v.z);
    t[rl][q * 4 + 3] = f2bf(v.w);
    __syncthreads();
    ushort4 o;
    o.x = t[q * 4 + 0][rl];
    o.y = t[q * 4 + 1][rl];
    o.z = t[q * 4 + 2][rl];
    o.w = t[q * 4 + 3][rl];
    *(ushort4*)&w1t[(size_t)(bx * 32 + rl) * D_EMB + by * 32 + q * 4] = o;
  } else {                                // ---- W2 per-expert transpose ----
    int b2 = b - 16384;
    int bx = b2 & 31, by = b2 >> 5;       // bx: d/32 (0..31), by: f-rows/32 (0..511)
    float4 v = *(const float4*)&w2[(size_t)(by * 32 + rl) * D_EMB + bx * 32 + q * 4];
    t[rl][q * 4 + 0] = f2bf(v.x);
    t[rl][q * 4 + 1] = f2bf(v.y);
    t[rl][q * 4 + 2] = f2bf(v.z);
    t[rl][q * 4 + 3] = f2bf(v.w);
    __syncthreads();
    int e = by >> 6;                      // 2048 f-rows per expert
    int f0 = (by & 63) * 32;
    size_t eoff = (size_t)e * (D_EMB * D_FFN);
    ushort4 o;
    o.x = t[q * 4 + 0][rl];
    o.y = t[q * 4 + 1][rl];
    o.z = t[q * 4 + 2][rl];
    o.w = t[q * 4 + 3][rl];
    *(ushort4*)&w2te[eoff + (size_t)(bx * 32 + rl) * D_FFN + f0 + q * 4] = o;
  }
}

__global__ void prefix_k(const int* __restrict__ counts, int* __restrict__ bases,
                         int* __restrict__ cursor) {
  if (threadIdx.x == 0) {
    int s = 0;
    for (int e = 0; e < NE; ++e) { bases[e] = s; cursor[e] = s; s += counts[e]; }
  }
}

// ---- scatter: two-phase; tokS[pos] = s (= token*2 + slot-index) ------------
__global__ __launch_bounds__(256) void scatter_k(const int* __restrict__ ti,
                                                 const float* __restrict__ tg,
                                                 int* __restrict__ cursor,
                                                 int* __restrict__ tokS,
                                                 float* __restrict__ gate) {
  __shared__ int lc[NE], lb[NE];
  if (threadIdx.x < NE) lc[threadIdx.x] = 0;
  __syncthreads();
  int s = blockIdx.x * 256 + threadIdx.x;
  int e = ti[s];
  float g = tg[s];
  int loc = atomicAdd(&lc[e], 1);
  __syncthreads();
  if (threadIdx.x < NE) lb[threadIdx.x] = atomicAdd(&cursor[threadIdx.x], lc[threadIdx.x]);
  __syncthreads();
  int pos = lb[e] + loc;
  tokS[pos] = s;
  gate[pos] = g;
}

// ===== 128x128 / BK=32 grouped GEMM, dbuf + counted vmcnt(4) [proven R7] ====
// Slot swizzle phys = slot ^ ((row>>1)&3), both-sides via pre-swizzled global
// col; measured 0 bank conflicts. STAGE(t+1) issues BEFORE waiting; VW(4)
// drains only tile t's 4 loads (issued one iteration earlier). Raw s_barriers.

#define STG(BUF)                                                           \
  { _Pragma("unroll") for (int j_ = 0; j_ < 2; ++j_) {                     \
      gll16(aptr[j_], &Al[BUF][ldso[j_]]);                                 \
      gll16(bptr[j_], &Bl[BUF][ldso[j_]]);                                 \
      aptr[j_] += BK; bptr[j_] += BK;                                      \
    } }

#define CMP(BUF)                                                           \
  { short8 a[4], b[4];                                                     \
    _Pragma("unroll") for (int i_ = 0; i_ < 4; ++i_)                       \
      a[i_] = *(const short8*)&Al[BUF][arow + i_ * 16 * BK];               \
    _Pragma("unroll") for (int j_ = 0; j_ < 4; ++j_)                       \
      b[j_] = *(const short8*)&Bl[BUF][brow + j_ * 16 * BK];               \
    _Pragma("unroll") for (int i_ = 0; i_ < 4; ++i_)                       \
      _Pragma("unroll") for (int j_ = 0; j_ < 4; ++j_)                     \
        acc[i_][j_] = __builtin_amdgcn_mfma_f32_16x16x32_bf16(a[i_], b[j_], acc[i_][j_], 0, 0, 0); \
  }

#define KLOOP(NT)                                                          \
  STG(0);                                                                  \
  for (int ks = 0; ks < (NT) - 2; ks += 2) {                               \
    STG(1); VW(4); BAR(); CMP(0); BAR();                                   \
    STG(0); VW(4); BAR(); CMP(1); BAR();                                   \
  }                                                                        \
  STG(1); VW(4); BAR(); CMP(0); BAR();                                     \
  VW(0); BAR(); CMP(1);

// ---------------- grouped GEMM1: h = gelu(x @ W1_e), gathered rows ----------
__global__ __launch_bounds__(256) void gemm1_k(const ushort* __restrict__ xb,
                                               const ushort* __restrict__ w1t,
                                               const int* __restrict__ counts,
                                               const int* __restrict__ bases,
                                               const int* __restrict__ tokS,
                                               ushort* __restrict__ h) {
  int bid = (int)blockIdx.x;
  bid = (bid & 7) * 512 + (bid >> 3);   // XCD-contiguous: 1 expert/XCD
  int e = bid >> 9;                     // 32 mt * 16 nt per expert (cap 4096 rows)
  int rem = bid & 511;
  int mt = rem >> 4, nt = rem & 15;
  int count = counts[e];
  if (mt * BM >= count) return;
  int base = bases[e];

  __shared__ ushort Al[2][BM * BK];
  __shared__ ushort Bl[2][BN * BK];

  int tid = threadIdx.x;
  int w = tid >> 6, lane = tid & 63;

  const int ssw = (((lane & 3) ^ ((lane >> 3) & 3))) * 8;

  const ushort* aptr[2]; const ushort* bptr[2];
  int ldso[2];
#pragma unroll
  for (int j = 0; j < 2; ++j) {
    int rl = w * 32 + j * 16 + (lane >> 2);
    int pr = min(base + mt * BM + rl, base + count - 1);
    int t = tokS[pr] >> 1;
    aptr[j] = xb + (size_t)t * D_EMB + ssw;
    int c = e * D_FFN + nt * BN + rl;
    bptr[j] = w1t + (size_t)c * D_EMB + ssw;
    ldso[j] = (w * 32 + j * 16) * BK;
  }

  f32x4 zero = {0.f, 0.f, 0.f, 0.f};
  f32x4 acc[4][4];
#pragma unroll
  for (int i = 0; i < 4; ++i)
#pragma unroll
    for (int j = 0; j < 4; ++j) acc[i][j] = zero;

  int wm = w >> 1, wn = w & 1;
  const int rsw = ((lane >> 4) ^ (((lane & 15) >> 1) & 3)) * 8;
  const int arow = (wm * 64 + (lane & 15)) * BK + rsw;
  const int brow = (wn * 64 + (lane & 15)) * BK + rsw;

  KLOOP(D_EMB / BK);   // 32 tiles

  int r0 = mt * BM + wm * 64, c0 = nt * BN + wn * 64;
#pragma unroll
  for (int i = 0; i < 4; ++i) {
#pragma unroll
    for (int q = 0; q < 4; ++q) {
      int row = r0 + i * 16 + (lane >> 4) * 4 + q;
      if (row < count) {
        size_t hb = (size_t)(base + row) * D_FFN;
#pragma unroll
        for (int j = 0; j < 4; ++j) {
          h[hb + c0 + j * 16 + (lane & 15)] = f2bf(gelu_f(acc[i][j][q]));
        }
      }
    }
  }
}

// -- grouped GEMM2: y2[tok*2+k] = gate * (h @ W2_e), token-major, bf16 -------
__global__ __launch_bounds__(256) void gemm2_k(const ushort* __restrict__ h,
                                               const ushort* __restrict__ w2te,
                                               const int* __restrict__ counts,
                                               const int* __restrict__ bases,
                                               const int* __restrict__ tokS,
                                               const float* __restrict__ gate,
                                               ushort* __restrict__ y2) {
  int bid = (int)blockIdx.x;
  bid = (bid & 7) * 256 + (bid >> 3);   // XCD-contiguous: 1 expert/XCD
  int e = bid >> 8;                     // 32 mt * 8 nt per expert (cap 4096 rows)
  int rem = bid & 255;
  int mt = rem >> 3, nt = rem & 7;
  int count = counts[e];
  if (mt * BM >= count) return;
  int base = bases[e];

  __shared__ ushort Al[2][BM * BK];
  __shared__ ushort Bl[2][BN * BK];

  int tid = threadIdx.x;
  int w = tid >> 6, lane = tid & 63;

  const int ssw = (((lane & 3) ^ ((lane >> 3) & 3))) * 8;

  const ushort* aptr[2]; const ushort* bptr[2];
  int ldso[2];
#pragma unroll
  for (int j = 0; j < 2; ++j) {
    int rl = w * 32 + j * 16 + (lane >> 2);
    int pr = min(base + mt * BM + rl, base + count - 1);
    aptr[j] = h + (size_t)pr * D_FFN + ssw;
    int d = nt * BN + rl;               // output column (embedding dim)
    bptr[j] = w2te + (size_t)e * (D_EMB * D_FFN) + (size_t)d * D_FFN + ssw;
    ldso[j] = (w * 32 + j * 16) * BK;
  }

  f32x4 zero = {0.f, 0.f, 0.f, 0.f};
  f32x4 acc[4][4];
#pragma unroll
  for (int i = 0; i < 4; ++i)
#pragma unroll
    for (int j = 0; j < 4; ++j) acc[i][j] = zero;

  int wm = w >> 1, wn = w & 1;
  const int rsw = ((lane >> 4) ^ (((lane & 15) >> 1) & 3)) * 8;
  const int arow = (wm * 64 + (lane & 15)) * BK + rsw;
  const int brow = (wn * 64 + (lane & 15)) * BK + rsw;

  KLOOP(D_FFN / BK);   // 64 tiles

  int r0 = mt * BM + wm * 64, c0 = nt * BN + wn * 64;
#pragma unroll
  for (int i = 0; i < 4; ++i) {
#pragma unroll
    for (int q = 0; q < 4; ++q) {
      int row = r0 + i * 16 + (lane >> 4) * 4 + q;
      if (row < count) {
        int pr = base + row;
        float g = gate[pr];
        size_t yb = (size_t)tokS[pr] * D_EMB;   // token-major: row = tok*2+k
#pragma unroll
        for (int j = 0; j < 4; ++j) {
          y2[yb + c0 + j * 16 + (lane & 15)] = f2bf(g * acc[i][j][q]);
        }
      }
    }
  }
}

// ---- combine: out[n] = y2[2n] + y2[2n+1] (streaming, gates pre-applied) ----
__global__ __launch_bounds__(256) void combine_k(const ushort* __restrict__ y2,
                                                 float* __restrict__ out) {
  int n = blockIdx.x;
  const ushort4* r0 = (const ushort4*)(y2 + (size_t)(2 * n) * D_EMB);
  const ushort4* r1 = (const ushort4*)(y2 + (size_t)(2 * n + 1) * D_EMB);
  float4* o = (float4*)(out + (size_t)n * D_EMB);
  int i = threadIdx.x;
  ushort4 a = r0[i], b = r1[i];
  float4 v;
  v.x = bf2f(a.x) + bf2f(b.x);
  v.y = bf2f(a.y) + bf2f(b.y);
  v.z = bf2f(a.z) + bf2f(b.z);
  v.w = bf2f(a.w) + bf2f(b.w);
  o[i] = v;
}

extern "C" void kernel_launch(void* const* d_in, const int* in_sizes, int n_in,
                              void* d_out, int out_size, void* d_ws, size_t ws_size,
                              hipStream_t stream) {
  const float* x  = (const float*)d_in[0];
  const float* rw = (const float*)d_in[1];
  const float* w1 = (const float*)d_in[2];
  const float* w2 = (const float*)d_in[3];
  float* out = (float*)d_out;

  char* ws = (char*)d_ws;
  size_t off = 0;
  auto alloc = [&](size_t bytes) {
    void* p = ws + off;
    off = (off + bytes + 255) & ~(size_t)255;
    return p;
  };
  int*    counts = (int*)alloc(32);
  int*    bases  = (int*)alloc(32);
  int*    cursor = (int*)alloc(32);
  int*    ti     = (int*)alloc((size_t)N_TOK * 2 * sizeof(int));
  float*  tg     = (float*)alloc((size_t)N_TOK * 2 * sizeof(float));
  int*    tokS   = (int*)alloc((size_t)N_TOK * 2 * sizeof(int));
  float*  gate   = (float*)alloc((size_t)N_TOK * 2 * sizeof(float));
  ushort* xb     = (ushort*)alloc((size_t)N_TOK * D_EMB * 2);
  ushort* w1t    = (ushort*)alloc((size_t)D_EMB * NE * D_FFN * 2);
  ushort* w2te   = (ushort*)alloc((size_t)D_EMB * NE * D_FFN * 2);
  ushort* hbuf   = (ushort*)alloc((size_t)N_TOK * 2 * D_FFN * 2);
  ushort* ybuf   = (ushort*)alloc((size_t)N_TOK * 2 * D_EMB * 2);
  (void)ws_size; (void)in_sizes; (void)n_in; (void)out_size;

  hipMemsetAsync(counts, 0, 32, stream);

  router_k<<<N_TOK / 4, 256, 0, stream>>>(x, rw, ti, tg, xb);
  prep_k<<<32800, 256, 0, stream>>>(w1, w2, ti, w1t, w2te, counts);
  prefix_k<<<1, 64, 0, stream>>>(counts, bases, cursor);
  scatter_k<<<N_TOK * 2 / 256, 256, 0, stream>>>(ti, tg, cursor, tokS, gate);
  gemm1_k<<<NE * 32 * 16, 256, 0, stream>>>(xb, w1t, counts, bases, tokS, hbuf);
  gemm2_k<<<NE * 32 * 8, 256, 0, stream>>>(hbuf, w2te, counts, bases, tokS, gate, ybuf);
  combine_k<<<N_TOK, 256, 0, stream>>>(ybuf, out);
}